// Round 1
// baseline (178.359 us; speedup 1.0000x reference)
//
#include <hip/hip_runtime.h>
#include <hip/hip_bf16.h>

#define BB  8
#define SCTX 4096
#define SQ  512
#define EE  300
#define HH  128
#define EP  320   // E padded to multiple of 32

typedef short short8 __attribute__((ext_vector_type(8)));
typedef float f32x4  __attribute__((ext_vector_type(4)));

#define MFMA16(a, b, c) __builtin_amdgcn_mfma_f32_16x16x32_bf16((a), (b), (c), 0, 0, 0)

// float -> bf16 bits, round-to-nearest-even (inputs are finite)
__device__ __forceinline__ short f2bf(float f) {
  unsigned u = __builtin_bit_cast(unsigned, f);
  u += 0x7fffu + ((u >> 16) & 1u);
  return (short)(u >> 16);
}

// Load one A-fragment (8 k-contiguous elems) from a global fp32 row, cvt to bf16.
// tail: k=288..319 region, guard k>=300 (Wpad has zeros there, but NaN*0=NaN).
__device__ __forceinline__ short8 load_a_bf16(const float* __restrict__ row, int k, bool tail) {
  short8 a;
  if (!tail) {
    const float4* p = (const float4*)(row + k);
    float4 x0 = p[0], x1 = p[1];
    a[0] = f2bf(x0.x); a[1] = f2bf(x0.y); a[2] = f2bf(x0.z); a[3] = f2bf(x0.w);
    a[4] = f2bf(x1.x); a[5] = f2bf(x1.y); a[6] = f2bf(x1.z); a[7] = f2bf(x1.w);
  } else {
#pragma unroll
    for (int j = 0; j < 8; ++j) a[j] = (k + j < EE) ? f2bf(row[k + j]) : (short)0;
  }
  return a;
}

// Dense: acc[n] += relu-less (row . Wpad[n*16+t]) over K=320 (10 MFMA k-steps)
__device__ __forceinline__ void dense_mfma(const float* __restrict__ arow,
                                           const short* __restrict__ wpad,
                                           f32x4* acc, int t, int quad) {
#pragma unroll
  for (int kk = 0; kk < 10; ++kk) {
    const int k = kk * 32 + quad * 8;
    short8 a = load_a_bf16(arow, k, kk == 9);
#pragma unroll
    for (int n = 0; n < 8; ++n) {
      short8 w8 = *(const short8*)(wpad + (n * 16 + t) * EP + k);
      acc[n] = MFMA16(a, w8, acc[n]);
    }
  }
}

// ---------------- kernel 0: W (fp32 [128][300]) -> bf16 padded [128][320] -------------
__global__ void k_wpad(const float* __restrict__ W, short* __restrict__ wpad) {
  const int h = blockIdx.x, k = threadIdx.x;
  float v = (k < EE) ? W[h * EE + k] : 0.0f;
  wpad[h * EP + k] = f2bf(v);
}

// ---------------- kernel 1: qst_logits = relu(qst @ W^T + b), stored as ql and qlT ----
__global__ __launch_bounds__(64) void k_qlog(const float* __restrict__ qst,
                                             const short* __restrict__ wpad,
                                             const float* __restrict__ bias,
                                             short* __restrict__ ql,
                                             short* __restrict__ qlT) {
  const int b = blockIdx.y;
  const int q0 = blockIdx.x * 16;
  const int l = threadIdx.x, t = l & 15, quad = l >> 4;
  const float* arow = qst + (size_t)(b * SQ + q0 + t) * EE;
  f32x4 acc[8] = {};
  dense_mfma(arow, wpad, acc, t, quad);
#pragma unroll
  for (int n = 0; n < 8; ++n) {
    const int h = n * 16 + t;
    const float bv = bias[h];
#pragma unroll
    for (int r = 0; r < 4; ++r) {
      float v = fmaxf(acc[n][r] + bv, 0.0f);
      short s16 = f2bf(v);
      const int q = q0 + quad * 4 + r;
      ql[(size_t)(b * SQ + q) * HH + h]  = s16;  // [b][q][h]
      qlT[(size_t)(b * HH + h) * SQ + q] = s16;  // [b][h][q]
    }
  }
}

// ---------------- kernel 2: fused dense(ctx) + QK^T + softmax + PV ---------------------
// grid (64, 8), block 256 = 4 waves; wave w owns ctx rows m0 + w*16 .. +15
__global__ __launch_bounds__(256, 2) void k_attn(const float* __restrict__ ctx,
                                                 const short* __restrict__ wpad,
                                                 const float* __restrict__ bias,
                                                 const int* __restrict__ mask,
                                                 const short* __restrict__ ql,
                                                 const short* __restrict__ qlT,
                                                 float* __restrict__ out) {
  const int b = blockIdx.y;
  const int m0 = blockIdx.x * 64;
  const int tid = threadIdx.x;
  const int w = tid >> 6, l = tid & 63, t = l & 15, quad = l >> 4;

  // per-wave-private tiles; stride 136 (=8*17) keeps ds_read_b128 at free 2-way conflicts
  __shared__ __align__(16) short cl[4][16 * 136];  // ctx_logits, A-layout [m][h]
  __shared__ __align__(16) short pb[4][16 * 136];  // P chunk,     A-layout [m][q]
  __shared__ float maskb[SQ];

  for (int i = tid; i < SQ; i += 256)
    maskb[i] = mask[b * SQ + i] ? 0.0f : -1e30f;
  // (published to all waves by the __syncthreads() after the dense phase)

  // ---- phase A: ctx_logits tile = relu(ctx @ W^T + b) ----
  const int mw = m0 + w * 16;
  const float* arow = ctx + (size_t)(b * SCTX + mw + t) * EE;
  f32x4 acc[8] = {};
  dense_mfma(arow, wpad, acc, t, quad);
#pragma unroll
  for (int n = 0; n < 8; ++n) {
    const int h = n * 16 + t;
    const float bv = bias[h];
#pragma unroll
    for (int r = 0; r < 4; ++r) {
      float v = fmaxf(acc[n][r] + bv, 0.0f);
      cl[w][(quad * 4 + r) * 136 + h] = f2bf(v);  // D-layout -> A-layout transpose
    }
  }
  __syncthreads();

  // ---- phase B: S[16][512] = CL @ QL^T, full row in registers ----
  short8 af[4];
#pragma unroll
  for (int kk = 0; kk < 4; ++kk)
    af[kk] = *(const short8*)&cl[w][t * 136 + kk * 32 + quad * 8];

  f32x4 s[32];
  const short* qbase = ql + (size_t)b * SQ * HH;
#pragma unroll
  for (int n = 0; n < 32; ++n) {
    f32x4 sv = {0.f, 0.f, 0.f, 0.f};
    const short* qb = qbase + (n * 16 + t) * HH;
#pragma unroll
    for (int kk = 0; kk < 4; ++kk) {
      short8 b8 = *(const short8*)(qb + kk * 32 + quad * 8);
      sv = MFMA16(af[kk], b8, sv);
    }
    const float mb = maskb[n * 16 + t];  // same q for all 4 rows of this reg
    sv[0] += mb; sv[1] += mb; sv[2] += mb; sv[3] += mb;
    s[n] = sv;
  }

  // ---- softmax over 512 (rows live on 16-lane groups; reduce with shfl_xor 1/2/4/8) --
  f32x4 rmax = s[0];
#pragma unroll
  for (int n = 1; n < 32; ++n)
#pragma unroll
    for (int r = 0; r < 4; ++r) rmax[r] = fmaxf(rmax[r], s[n][r]);
#pragma unroll
  for (int off = 8; off; off >>= 1)
#pragma unroll
    for (int r = 0; r < 4; ++r) rmax[r] = fmaxf(rmax[r], __shfl_xor(rmax[r], off));

  f32x4 rsum = {0.f, 0.f, 0.f, 0.f};
#pragma unroll
  for (int n = 0; n < 32; ++n)
#pragma unroll
    for (int r = 0; r < 4; ++r) {
      float p = exp2f((s[n][r] - rmax[r]) * 1.44269504f);
      s[n][r] = p;
      rsum[r] += p;
    }
#pragma unroll
  for (int off = 8; off; off >>= 1)
#pragma unroll
    for (int r = 0; r < 4; ++r) rsum[r] += __shfl_xor(rsum[r], off);

  // ---- phase C: O = P @ V in 4 q-chunks of 128 (P round-trips LDS for A-layout) ------
  f32x4 o[8] = {};
  const short* vbase = qlT + (size_t)b * HH * SQ;
#pragma unroll
  for (int c = 0; c < 4; ++c) {
#pragma unroll
    for (int n2 = 0; n2 < 8; ++n2)
#pragma unroll
      for (int r = 0; r < 4; ++r)
        pb[w][(quad * 4 + r) * 136 + n2 * 16 + t] = f2bf(s[c * 8 + n2][r]);
    // per-wave private region: in-wave DS ordering + compiler waitcnt suffice, no barrier
#pragma unroll
    for (int kk = 0; kk < 4; ++kk) {
      short8 pa = *(const short8*)&pb[w][t * 136 + kk * 32 + quad * 8];
#pragma unroll
      for (int n = 0; n < 8; ++n) {
        short8 v8 = *(const short8*)(vbase + (n * 16 + t) * SQ + c * 128 + kk * 32 + quad * 8);
        o[n] = MFMA16(pa, v8, o[n]);
      }
    }
  }

  // ---- epilogue: divide by row sum, store fp32 ----
  f32x4 rinv;
#pragma unroll
  for (int r = 0; r < 4; ++r) rinv[r] = 1.0f / rsum[r];
  float* obase = out + (size_t)(b * SCTX + mw) * HH;
#pragma unroll
  for (int n = 0; n < 8; ++n)
#pragma unroll
    for (int r = 0; r < 4; ++r)
      obase[(quad * 4 + r) * HH + n * 16 + t] = o[n][r] * rinv[r];
}

extern "C" void kernel_launch(void* const* d_in, const int* in_sizes, int n_in,
                              void* d_out, int out_size, void* d_ws, size_t ws_size,
                              hipStream_t stream) {
  const float* ctx  = (const float*)d_in[0];
  const float* qst  = (const float*)d_in[1];
  const int*   mask = (const int*)d_in[2];
  const float* W    = (const float*)d_in[3];
  const float* bias = (const float*)d_in[4];
  float* out = (float*)d_out;

  // workspace: Wpad bf16 (80 KiB) | ql bf16 (1 MiB) | qlT bf16 (1 MiB)
  short* wpad = (short*)d_ws;
  short* ql   = (short*)((char*)d_ws + 81920);
  short* qlT  = (short*)((char*)d_ws + 81920 + (size_t)BB * SQ * HH * 2);

  k_wpad<<<dim3(HH), dim3(EP), 0, stream>>>(W, wpad);
  k_qlog<<<dim3(SQ / 16, BB), dim3(64), 0, stream>>>(qst, wpad, bias, ql, qlT);
  k_attn<<<dim3(SCTX / 64, BB), dim3(256), 0, stream>>>(ctx, wpad, bias, mask, ql, qlT, out);
}

// Round 3
// 177.190 us; speedup vs baseline: 1.0066x; 1.0066x over previous
//
#include <hip/hip_runtime.h>
#include <hip/hip_bf16.h>

#define BB   8
#define SCTX 4096
#define SQ   512
#define EE   300
#define HH   128
#define EP   320    // E padded to multiple of 32
#define CST  328    // staged-ctx LDS stride (shorts)
#define PST  520    // P-buffer LDS stride (shorts), 16B-aligned rows, odd 16B-stride
#define LOG2E 1.4426950408889634f

typedef short short8 __attribute__((ext_vector_type(8)));
typedef float f32x4  __attribute__((ext_vector_type(4)));

#define MFMA16(a, b, c) __builtin_amdgcn_mfma_f32_16x16x32_bf16((a), (b), (c), 0, 0, 0)

__device__ __forceinline__ short f2bf(float f) {
  unsigned u = __builtin_bit_cast(unsigned, f);
  u += 0x7fffu + ((u >> 16) & 1u);
  return (short)(u >> 16);
}

// R1-proven: A-fragment (8 k-contiguous elems) from a global fp32 row, cvt to bf16.
__device__ __forceinline__ short8 load_a_bf16(const float* __restrict__ row, int k, bool tail) {
  short8 a;
  if (!tail) {
    const float4* p = (const float4*)(row + k);
    float4 x0 = p[0], x1 = p[1];
    a[0] = f2bf(x0.x); a[1] = f2bf(x0.y); a[2] = f2bf(x0.z); a[3] = f2bf(x0.w);
    a[4] = f2bf(x1.x); a[5] = f2bf(x1.y); a[6] = f2bf(x1.z); a[7] = f2bf(x1.w);
  } else {
#pragma unroll
    for (int j = 0; j < 8; ++j) a[j] = (k + j < EE) ? f2bf(row[k + j]) : (short)0;
  }
  return a;
}

// ---------------- kernel 0: W (fp32 [128][300]) -> bf16 padded [128][320] -------------
__global__ void k_wpad(const float* __restrict__ W, short* __restrict__ wpad) {
  const int h = blockIdx.x, k = threadIdx.x;
  float v = (k < EE) ? W[h * EE + k] : 0.0f;
  wpad[h * EP + k] = f2bf(v);
}

// ---------------- kernel 1: qst_logits = relu(qst @ W^T + b) -> ql [b][q][h], qlT [b][h][q]
// grid (SQ/16, B), 512 threads = 8 waves; wave w computes h-tile n = w (16 h-cols).
__global__ __launch_bounds__(512) void k_qlog(const float* __restrict__ qst,
                                              const short* __restrict__ wpad,
                                              const float* __restrict__ bias,
                                              short* __restrict__ ql,
                                              short* __restrict__ qlT) {
  const int b = blockIdx.y;
  const int q0 = blockIdx.x * 16;
  const int tid = threadIdx.x;
  const int w = tid >> 6, l = tid & 63, t = l & 15, quad = l >> 4;

  const float* arow = qst + (size_t)(b * SQ + q0 + t) * EE;
  const short* wrow = wpad + (w * 16 + t) * EP;
  f32x4 acc = {};
#pragma unroll
  for (int kk = 0; kk < 10; ++kk) {
    const int k = kk * 32 + quad * 8;
    short8 a = load_a_bf16(arow, k, kk == 9);
    short8 w8 = *(const short8*)(wrow + k);
    acc = MFMA16(a, w8, acc);
  }
  const int h = w * 16 + t;
  const float bv = bias[h];
  short4 v4;
  short* pv = (short*)&v4;
#pragma unroll
  for (int r = 0; r < 4; ++r) {
    float v = fmaxf(acc[r] + bv, 0.0f);
    short s16 = f2bf(v);
    pv[r] = s16;
    ql[(size_t)(b * SQ + q0 + quad * 4 + r) * HH + h] = s16;
  }
  *(short4*)(qlT + (size_t)(b * HH + h) * SQ + q0 + quad * 4) = v4;
}

// ---------------- kernel 2: fused dense(ctx) + QK^T + softmax + PV ---------------------
// grid (SCTX/32, B), block 256 = 4 waves; wave w: group g = w>>1 (16 ctx rows), hf = w&1.
// Phase A: h-split by hf.  Phase B: q-split by hf (256 q each).  Phase C: h-split by hf,
// full q=512 read from shared per-group P buffer (barrier-separated, no combine needed).
//
// LDS union u[16640] shorts (all crossings barrier-separated, same elem type except
// maskb which is dead before its region is reused):
//   cst  = u[0..10496)        staged ctx [32][CST]     : write pre-b1, read pre-b2
//   cl   = u[10496..14848)    ctx_logits [2][16][136]  : write b1..b2, read b2..b3
//   maskb= u[14848..15872)    fp32 [512]               : write pre-b1, read b2..b3
//   Pg   = u[0..16640)        P bf16 [2][16][PST]      : write b3..b4, read post-b4
__global__ __launch_bounds__(256, 4) void k_attn(const float* __restrict__ ctx,
                                                 const short* __restrict__ wpad,
                                                 const float* __restrict__ bias,
                                                 const int* __restrict__ mask,
                                                 const short* __restrict__ ql,
                                                 const short* __restrict__ qlT,
                                                 float* __restrict__ out) {
  const int b = blockIdx.y;
  const int m0 = blockIdx.x * 32;
  const int tid = threadIdx.x;
  const int w = tid >> 6, l = tid & 63, t = l & 15, quad = l >> 4;
  const int g = w >> 1, hf = w & 1;

  __shared__ __align__(16) short u[16640];
  __shared__ float sm[2][2][16][2];  // [g][hf][row][{max,sum}]

  short* cst = u;
  short* cl = u + 10496;
  float* maskb = (float*)(u + 14848);
  short* Pg = u;

  // ---- stage: 32 ctx rows coalesced fp32->bf16, explicit zero tail, mask bias ----
  const float4* cbase = (const float4*)(ctx + (size_t)(b * SCTX + m0) * EE);
#pragma unroll
  for (int j = 0; j < 10; ++j) {
    int i4 = tid + j * 256;
    if (i4 < 2400) {
      float4 v = cbase[i4];
      int row = i4 / 75, c4 = i4 - row * 75;
      short* dst = cst + row * CST + c4 * 4;
      dst[0] = f2bf(v.x); dst[1] = f2bf(v.y); dst[2] = f2bf(v.z); dst[3] = f2bf(v.w);
    }
  }
  for (int i = tid; i < 320; i += 256) {  // zero k=300..319 for ALL 32 rows
    int row = i / 10, c = (i - row * 10) * 2;
    cst[row * CST + 300 + c] = 0;
    cst[row * CST + 301 + c] = 0;
  }
  for (int i = tid; i < SQ; i += 256)
    maskb[i] = mask[b * SQ + i] ? 0.0f : -1e30f;
  __syncthreads();  // b1

  // ---- phase A: ctx_logits tile; wave pair splits h ----
  {
    const short* arow = cst + (g * 16 + t) * CST;
    f32x4 acc[4] = {};
#pragma unroll
    for (int kk = 0; kk < 10; ++kk) {
      const int k = kk * 32 + quad * 8;
      short8 a = *(const short8*)(arow + k);
#pragma unroll
      for (int n = 0; n < 4; ++n) {
        short8 w8 = *(const short8*)(wpad + ((hf * 4 + n) * 16 + t) * EP + k);
        acc[n] = MFMA16(a, w8, acc[n]);
      }
    }
#pragma unroll
    for (int n = 0; n < 4; ++n) {
      const int h = (hf * 4 + n) * 16 + t;
      const float bv = bias[h];
#pragma unroll
      for (int r = 0; r < 4; ++r) {
        float v = fmaxf(acc[n][r] + bv, 0.0f);
        cl[g * 2176 + (quad * 4 + r) * 136 + h] = f2bf(v);  // D-layout -> A-layout
      }
    }
  }
  __syncthreads();  // b2

  // ---- phase B: S[16 rows][256 q] for this wave's q-half ----
  short8 af[4];
#pragma unroll
  for (int kk = 0; kk < 4; ++kk)
    af[kk] = *(const short8*)&cl[g * 2176 + t * 136 + kk * 32 + quad * 8];

  f32x4 s[16];
  const short* qbase = ql + ((size_t)b * SQ + hf * 256) * HH;
#pragma unroll
  for (int n = 0; n < 16; ++n) {
    f32x4 sv = {0.f, 0.f, 0.f, 0.f};
    const short* qb = qbase + (n * 16 + t) * HH;
#pragma unroll
    for (int kk = 0; kk < 4; ++kk) {
      short8 b8 = *(const short8*)(qb + kk * 32 + quad * 8);
      sv = MFMA16(af[kk], b8, sv);
    }
    const float mb = maskb[hf * 256 + n * 16 + t];
    sv[0] += mb; sv[1] += mb; sv[2] += mb; sv[3] += mb;
    s[n] = sv;
  }

  // ---- softmax pass 1: local row max, butterfly over t, exchange ----
  f32x4 rmax = s[0];
#pragma unroll
  for (int n = 1; n < 16; ++n)
#pragma unroll
    for (int r = 0; r < 4; ++r) rmax[r] = fmaxf(rmax[r], s[n][r]);
#pragma unroll
  for (int off = 8; off; off >>= 1)
#pragma unroll
    for (int r = 0; r < 4; ++r) rmax[r] = fmaxf(rmax[r], __shfl_xor(rmax[r], off));
  if (t == 0) {
#pragma unroll
    for (int r = 0; r < 4; ++r) sm[g][hf][quad * 4 + r][0] = rmax[r];
  }
  __syncthreads();  // b3

  // ---- softmax pass 2: exp with TRUE max, local sum, exchange; P -> shared LDS ----
  f32x4 mc;
#pragma unroll
  for (int r = 0; r < 4; ++r) mc[r] = fmaxf(rmax[r], sm[g][hf ^ 1][quad * 4 + r][0]);

  f32x4 rsum = {0.f, 0.f, 0.f, 0.f};
#pragma unroll
  for (int n = 0; n < 16; ++n)
#pragma unroll
    for (int r = 0; r < 4; ++r) {
      float p = exp2f((s[n][r] - mc[r]) * LOG2E);
      s[n][r] = p;
      rsum[r] += p;
    }
#pragma unroll
  for (int off = 8; off; off >>= 1)
#pragma unroll
    for (int r = 0; r < 4; ++r) rsum[r] += __shfl_xor(rsum[r], off);
  if (t == 0) {
#pragma unroll
    for (int r = 0; r < 4; ++r) sm[g][hf][quad * 4 + r][1] = rsum[r];
  }
#pragma unroll
  for (int n = 0; n < 16; ++n)
#pragma unroll
    for (int r = 0; r < 4; ++r)
      Pg[(g * 16 + quad * 4 + r) * PST + hf * 256 + n * 16 + t] = f2bf(s[n][r]);
  __syncthreads();  // b4

  f32x4 rinv;
#pragma unroll
  for (int r = 0; r < 4; ++r)
    rinv[r] = 1.0f / (rsum[r] + sm[g][hf ^ 1][quad * 4 + r][1]);

  // ---- phase C: O[16 rows][64 h] = P(full 512 q) @ V; wave pair splits h ----
  f32x4 o[4] = {};
  const short* vbase = qlT + (size_t)b * HH * SQ;
#pragma unroll
  for (int kk = 0; kk < 16; ++kk) {
    short8 pa = *(const short8*)&Pg[(g * 16 + t) * PST + kk * 32 + quad * 8];
#pragma unroll
    for (int n = 0; n < 4; ++n) {
      short8 v8 = *(const short8*)(vbase + ((hf * 4 + n) * 16 + t) * SQ + kk * 32 + quad * 8);
      o[n] = MFMA16(pa, v8, o[n]);
    }
  }

  // ---- epilogue: divide by combined sum, store fp32 (each wave owns its h-half) ----
  float* obase = out + (size_t)(b * SCTX + m0 + g * 16) * HH;
#pragma unroll
  for (int n = 0; n < 4; ++n)
#pragma unroll
    for (int r = 0; r < 4; ++r)
      obase[(quad * 4 + r) * HH + (hf * 4 + n) * 16 + t] = o[n][r] * rinv[r];
}

extern "C" void kernel_launch(void* const* d_in, const int* in_sizes, int n_in,
                              void* d_out, int out_size, void* d_ws, size_t ws_size,
                              hipStream_t stream) {
  const float* ctx  = (const float*)d_in[0];
  const float* qst  = (const float*)d_in[1];
  const int*   mask = (const int*)d_in[2];
  const float* W    = (const float*)d_in[3];
  const float* bias = (const float*)d_in[4];
  float* out = (float*)d_out;

  short* wpad = (short*)d_ws;
  short* ql   = (short*)((char*)d_ws + 81920);
  short* qlT  = (short*)((char*)d_ws + 81920 + (size_t)BB * SQ * HH * 2);

  k_wpad<<<dim3(HH), dim3(EP), 0, stream>>>(W, wpad);
  k_qlog<<<dim3(SQ / 16, BB), dim3(512), 0, stream>>>(qst, wpad, bias, ql, qlT);
  k_attn<<<dim3(SCTX / 32, BB), dim3(256), 0, stream>>>(ctx, wpad, bias, mask, ql, qlT, out);
}

// Round 4
// 155.944 us; speedup vs baseline: 1.1437x; 1.1362x over previous
//
#include <hip/hip_runtime.h>
#include <hip/hip_bf16.h>

#define BB   8
#define SCTX 4096
#define SQ   512
#define EE   300
#define HH   128
#define EP   320    // E padded to multiple of 32
#define CST  328    // staged fp32->bf16 E-row stride (shorts)
#define LOG2E 1.4426950408889634f

typedef short short8 __attribute__((ext_vector_type(8)));
typedef float f32x4  __attribute__((ext_vector_type(4)));

#define MFMA16(a, b, c) __builtin_amdgcn_mfma_f32_16x16x32_bf16((a), (b), (c), 0, 0, 0)

__device__ __forceinline__ short f2bf(float f) {
  unsigned u = __builtin_bit_cast(unsigned, f);
  u += 0x7fffu + ((u >> 16) & 1u);
  return (short)(u >> 16);
}

// ---------------- kernel 0: W (fp32 [128][300]) -> bf16 padded [128][320] -------------
__global__ void k_wpad(const float* __restrict__ W, short* __restrict__ wpad) {
  const int h = blockIdx.x, k = threadIdx.x;
  float v = (k < EE) ? W[h * EE + k] : 0.0f;
  wpad[h * EP + k] = f2bf(v);
}

// ---------------- kernel 1: logits = relu(X @ W^T + b) for 32 rows/block --------------
// grid (NR/32, B), block 256 = 4 waves; wave w: g=w>>1 row-group, hf=w&1 h-half.
// dst  = [b][row][h] bf16 ; dstT (nullable) = [b][h][row] bf16 (row dim = SQ).
__global__ __launch_bounds__(256) void k_logits(const float* __restrict__ src,
                                                const short* __restrict__ wpad,
                                                const float* __restrict__ bias,
                                                const int NR,
                                                short* __restrict__ dst,
                                                short* __restrict__ dstT) {
  const int b = blockIdx.y;
  const int m0 = blockIdx.x * 32;
  const int tid = threadIdx.x;
  const int w = tid >> 6, l = tid & 63, t = l & 15, quad = l >> 4;
  const int g = w >> 1, hf = w & 1;

  __shared__ __align__(16) short cst[32 * CST];

  // stage 32 rows x 300 fp32 -> bf16 (coalesced float4), zero tail k=300..319
  const float4* cbase = (const float4*)(src + (size_t)(b * NR + m0) * EE);
#pragma unroll
  for (int j = 0; j < 10; ++j) {
    int i4 = tid + j * 256;
    if (i4 < 2400) {
      float4 v = cbase[i4];
      int row = i4 / 75, c4 = i4 - row * 75;
      short* dp = cst + row * CST + c4 * 4;
      dp[0] = f2bf(v.x); dp[1] = f2bf(v.y); dp[2] = f2bf(v.z); dp[3] = f2bf(v.w);
    }
  }
  for (int i = tid; i < 320; i += 256) {
    int row = i / 10, c = (i - row * 10) * 2;
    cst[row * CST + 300 + c] = 0;
    cst[row * CST + 301 + c] = 0;
  }
  __syncthreads();

  const short* arow = cst + (g * 16 + t) * CST;
  f32x4 acc[4] = {};
#pragma unroll
  for (int kk = 0; kk < 10; ++kk) {
    const int k = kk * 32 + quad * 8;
    short8 a = *(const short8*)(arow + k);
#pragma unroll
    for (int n = 0; n < 4; ++n) {
      short8 w8 = *(const short8*)(wpad + ((hf * 4 + n) * 16 + t) * EP + k);
      acc[n] = MFMA16(a, w8, acc[n]);
    }
  }
#pragma unroll
  for (int n = 0; n < 4; ++n) {
    const int h = (hf * 4 + n) * 16 + t;
    const float bv = bias[h];
#pragma unroll
    for (int r = 0; r < 4; ++r) {
      float v = fmaxf(acc[n][r] + bv, 0.0f);
      short s16 = f2bf(v);
      const int row = m0 + g * 16 + quad * 4 + r;
      dst[((size_t)b * NR + row) * HH + h] = s16;
      if (dstT) dstT[((size_t)b * HH + h) * SQ + row] = s16;
    }
  }
}

// ---------------- kernel 2: S = CL@QL^T, softmax, O = P@QL (all LDS-staged) -----------
// grid (SCTX/64, B), block 256 = 4 waves; wave w owns ctx rows m0+w*16..+15, full q=512.
// LDS: ubuf = [clt 64x136 | qch 128x136], pb aliases clt (dead after af load).
__global__ __launch_bounds__(256, 2) void k_attn(const short* __restrict__ cl,
                                                 const short* __restrict__ ql,
                                                 const short* __restrict__ qlT,
                                                 const int* __restrict__ mask,
                                                 float* __restrict__ out) {
  const int b = blockIdx.y;
  const int m0 = blockIdx.x * 64;
  const int tid = threadIdx.x;
  const int w = tid >> 6, l = tid & 63, t = l & 15, quad = l >> 4;

  __shared__ __align__(16) short ubuf[8704 + 17408];
  __shared__ float maskb[SQ];
  short* clt = ubuf;          // [64][136] A-tile (rows m, k=h)
  short* pb  = ubuf;          // [4][16*136] per-wave P tiles (aliases clt)
  short* qch = ubuf + 8704;   // [128][136] staged QL / QLT chunk

  // ---- stage CL tile: 64 rows x 128 sh = 1024 16B-units, coalesced ----
  {
    const short8* srcv = (const short8*)(cl + ((size_t)b * SCTX + m0) * HH);
#pragma unroll
    for (int j = 0; j < 4; ++j) {
      int i = tid + j * 256;
      int row = i >> 4, c16 = i & 15;
      *(short8*)&clt[row * 136 + c16 * 8] = srcv[i];
    }
  }
  for (int i = tid; i < SQ; i += 256)
    maskb[i] = mask[b * SQ + i] ? 0.0f : -1e30f;
  __syncthreads();

  // A-fragments for this wave's 16 rows (clt dead afterwards)
  short8 af[4];
#pragma unroll
  for (int kk = 0; kk < 4; ++kk)
    af[kk] = *(const short8*)&clt[(w * 16 + t) * 136 + kk * 32 + quad * 8];

  // ---- phase B: S in 4 q-chunks of 128, staged through LDS ----
  f32x4 s[32];
#pragma unroll
  for (int c = 0; c < 4; ++c) {
    __syncthreads();  // previous chunk readers (and af loads for c=0) done
    {
      const short8* srcv = (const short8*)(ql + ((size_t)b * SQ + c * 128) * HH);
#pragma unroll
      for (int j = 0; j < 8; ++j) {
        int i = tid + j * 256;
        int row = i >> 4, c16 = i & 15;
        *(short8*)&qch[row * 136 + c16 * 8] = srcv[i];
      }
    }
    __syncthreads();
#pragma unroll
    for (int n2 = 0; n2 < 8; ++n2) {
      f32x4 sv = {0.f, 0.f, 0.f, 0.f};
      const short* qrow = qch + (n2 * 16 + t) * 136;
#pragma unroll
      for (int kk = 0; kk < 4; ++kk) {
        short8 b8 = *(const short8*)(qrow + kk * 32 + quad * 8);
        sv = MFMA16(af[kk], b8, sv);
      }
      s[c * 8 + n2] = sv;
    }
  }

  // ---- mask bias + wave-local softmax (rows on 16-lane groups) ----
#pragma unroll
  for (int n = 0; n < 32; ++n) {
    const float mb = maskb[(n >> 3) * 128 + (n & 7) * 16 + t];
    s[n][0] += mb; s[n][1] += mb; s[n][2] += mb; s[n][3] += mb;
  }
  f32x4 rmax = s[0];
#pragma unroll
  for (int n = 1; n < 32; ++n)
#pragma unroll
    for (int r = 0; r < 4; ++r) rmax[r] = fmaxf(rmax[r], s[n][r]);
#pragma unroll
  for (int off = 8; off; off >>= 1)
#pragma unroll
    for (int r = 0; r < 4; ++r) rmax[r] = fmaxf(rmax[r], __shfl_xor(rmax[r], off));

  f32x4 rsum = {0.f, 0.f, 0.f, 0.f};
#pragma unroll
  for (int n = 0; n < 32; ++n)
#pragma unroll
    for (int r = 0; r < 4; ++r) {
      float p = exp2f((s[n][r] - rmax[r]) * LOG2E);
      s[n][r] = p;
      rsum[r] += p;
    }
#pragma unroll
  for (int off = 8; off; off >>= 1)
#pragma unroll
    for (int r = 0; r < 4; ++r) rsum[r] += __shfl_xor(rsum[r], off);

  // ---- phase C: O += P_chunk @ V_chunk, V staged from qlT, P via wave-private LDS ----
  f32x4 o[8] = {};
  short* pbw = pb + w * 2176;
#pragma unroll
  for (int c = 0; c < 4; ++c) {
    __syncthreads();  // previous chunk readers done
    {
      const short8* srcv = (const short8*)(qlT + (size_t)b * HH * SQ + c * 128);
#pragma unroll
      for (int j = 0; j < 8; ++j) {
        int i = tid + j * 256;
        int row = i >> 4, c16 = i & 15;
        *(short8*)&qch[row * 136 + c16 * 8] = srcv[row * 64 + c16];
      }
    }
    __syncthreads();
    // P: D-layout regs -> A-layout LDS (wave-private region, in-wave ordering suffices)
#pragma unroll
    for (int n2 = 0; n2 < 8; ++n2)
#pragma unroll
      for (int r = 0; r < 4; ++r)
        pbw[(quad * 4 + r) * 136 + n2 * 16 + t] = f2bf(s[c * 8 + n2][r]);
#pragma unroll
    for (int kk = 0; kk < 4; ++kk) {
      short8 pa = *(const short8*)&pbw[t * 136 + kk * 32 + quad * 8];
#pragma unroll
      for (int n = 0; n < 8; ++n) {
        short8 v8 = *(const short8*)&qch[(n * 16 + t) * 136 + kk * 32 + quad * 8];
        o[n] = MFMA16(pa, v8, o[n]);
      }
    }
  }

  // ---- epilogue ----
  f32x4 rinv;
#pragma unroll
  for (int r = 0; r < 4; ++r) rinv[r] = 1.0f / rsum[r];
  float* obase = out + ((size_t)b * SCTX + m0 + w * 16) * HH;
#pragma unroll
  for (int n = 0; n < 8; ++n)
#pragma unroll
    for (int r = 0; r < 4; ++r)
      obase[(quad * 4 + r) * HH + n * 16 + t] = o[n][r] * rinv[r];
}

extern "C" void kernel_launch(void* const* d_in, const int* in_sizes, int n_in,
                              void* d_out, int out_size, void* d_ws, size_t ws_size,
                              hipStream_t stream) {
  const float* ctx  = (const float*)d_in[0];
  const float* qst  = (const float*)d_in[1];
  const int*   mask = (const int*)d_in[2];
  const float* W    = (const float*)d_in[3];
  const float* bias = (const float*)d_in[4];
  float* out = (float*)d_out;

  // ws: wpad 80 KiB | cl 8 MiB | ql 1 MiB | qlT 1 MiB
  short* wpad = (short*)d_ws;
  short* cl   = (short*)((char*)d_ws + 81920);
  short* ql   = (short*)((char*)d_ws + 81920 + (size_t)BB * SCTX * HH * 2);
  short* qlT  = ql + (size_t)BB * SQ * HH;

  k_wpad<<<dim3(HH), dim3(EP), 0, stream>>>(W, wpad);
  k_logits<<<dim3(SCTX / 32, BB), dim3(256), 0, stream>>>(ctx, wpad, bias, SCTX, cl, nullptr);
  k_logits<<<dim3(SQ / 32, BB), dim3(256), 0, stream>>>(qst, wpad, bias, SQ, ql, qlT);
  k_attn<<<dim3(SCTX / 64, BB), dim3(256), 0, stream>>>(cl, ql, qlT, mask, out);
}

// Round 5
// 130.527 us; speedup vs baseline: 1.3665x; 1.1947x over previous
//
#include <hip/hip_runtime.h>
#include <hip/hip_bf16.h>

#define BB   8
#define SCTX 4096
#define SQ   512
#define EE   300
#define HH   128
#define EP   320    // E padded to multiple of 32
#define CST  328    // staged fp32->bf16 E-row stride (shorts)
#define LOG2E 1.4426950408889634f

typedef short short8 __attribute__((ext_vector_type(8)));
typedef float f32x4  __attribute__((ext_vector_type(4)));

#define MFMA16(a, b, c) __builtin_amdgcn_mfma_f32_16x16x32_bf16((a), (b), (c), 0, 0, 0)

__device__ __forceinline__ short f2bf(float f) {
  unsigned u = __builtin_bit_cast(unsigned, f);
  u += 0x7fffu + ((u >> 16) & 1u);
  return (short)(u >> 16);
}

// ---------------- kernel 0: W (fp32 [128][300]) -> bf16 padded [128][320] -------------
__global__ void k_wpad(const float* __restrict__ W, short* __restrict__ wpad) {
  const int h = blockIdx.x, k = threadIdx.x;
  float v = (k < EE) ? W[h * EE + k] : 0.0f;
  wpad[h * EP + k] = f2bf(v);
}

// ---------------- kernel 1: qst logits = relu(qst @ W^T + b) -> ql [b][q][h], qlT [b][h][q]
// grid (SQ/32, B), block 256 = 4 waves; wave w: g=w>>1 row-group, hf=w&1 h-half.
__global__ __launch_bounds__(256) void k_qlog(const float* __restrict__ qst,
                                              const short* __restrict__ wpad,
                                              const float* __restrict__ bias,
                                              short* __restrict__ ql,
                                              short* __restrict__ qlT) {
  const int b = blockIdx.y;
  const int m0 = blockIdx.x * 32;
  const int tid = threadIdx.x;
  const int w = tid >> 6, l = tid & 63, t = l & 15, quad = l >> 4;
  const int g = w >> 1, hf = w & 1;

  __shared__ __align__(16) short cst[32 * CST];

  const float4* cbase = (const float4*)(qst + (size_t)(b * SQ + m0) * EE);
#pragma unroll
  for (int j = 0; j < 10; ++j) {
    int i4 = tid + j * 256;
    if (i4 < 2400) {
      float4 v = cbase[i4];
      int row = i4 / 75, c4 = i4 - row * 75;
      short* dp = cst + row * CST + c4 * 4;
      dp[0] = f2bf(v.x); dp[1] = f2bf(v.y); dp[2] = f2bf(v.z); dp[3] = f2bf(v.w);
    }
  }
  for (int i = tid; i < 320; i += 256) {
    int row = i / 10, c = (i - row * 10) * 2;
    cst[row * CST + 300 + c] = 0;
    cst[row * CST + 301 + c] = 0;
  }
  __syncthreads();

  const short* arow = cst + (g * 16 + t) * CST;
  f32x4 acc[4] = {};
#pragma unroll
  for (int kk = 0; kk < 10; ++kk) {
    const int k = kk * 32 + quad * 8;
    short8 a = *(const short8*)(arow + k);
#pragma unroll
    for (int n = 0; n < 4; ++n) {
      short8 w8 = *(const short8*)(wpad + ((hf * 4 + n) * 16 + t) * EP + k);
      acc[n] = MFMA16(a, w8, acc[n]);
    }
  }
#pragma unroll
  for (int n = 0; n < 4; ++n) {
    const int h = (hf * 4 + n) * 16 + t;
    const float bv = bias[h];
#pragma unroll
    for (int r = 0; r < 4; ++r) {
      float v = fmaxf(acc[n][r] + bv, 0.0f);
      short s16 = f2bf(v);
      const int row = m0 + g * 16 + quad * 4 + r;
      ql[((size_t)b * SQ + row) * HH + h] = s16;
      qlT[((size_t)b * HH + h) * SQ + row] = s16;
    }
  }
}

// ---------------- kernel 2: fused ctx-logits + QK^T + softmax + PV ---------------------
// grid (SCTX/64, B), block 256 = 4 waves; wave w owns ctx rows m0+w*16..+15, full q=512.
// LDS: uq = cst (phase A, 32-row staging) / qch (phases B,C); uc = clt (A..af) / pb (C).
__global__ __launch_bounds__(256, 2) void k_attn(const float* __restrict__ ctx,
                                                 const short* __restrict__ wpad,
                                                 const float* __restrict__ bias,
                                                 const int* __restrict__ mask,
                                                 const short* __restrict__ ql,
                                                 const short* __restrict__ qlT,
                                                 float* __restrict__ out) {
  const int b = blockIdx.y;
  const int m0 = blockIdx.x * 64;
  const int tid = threadIdx.x;
  const int w = tid >> 6, l = tid & 63, t = l & 15, quad = l >> 4;
  const int g = w >> 1, hf = w & 1;

  __shared__ __align__(16) short uq[17408];  // cst [32][CST] -> qch [128][136]
  __shared__ __align__(16) short uc[8704];   // clt [64][136] -> pb [4][16*136]
  __shared__ float maskb[SQ];
  short* cst = uq;
  short* qch = uq;
  short* clt = uc;
  short* pbw = uc + w * 2176;

  for (int i = tid; i < SQ; i += 256)
    maskb[i] = mask[b * SQ + i] ? 0.0f : -1e30f;

  // ---- phase A: ctx_logits tile [64][128], two 32-row halves ----
  for (int i = 0; i < 2; ++i) {
    const float4* cbase = (const float4*)(ctx + ((size_t)b * SCTX + m0 + i * 32) * EE);
#pragma unroll
    for (int j = 0; j < 10; ++j) {
      int i4 = tid + j * 256;
      if (i4 < 2400) {
        float4 v = cbase[i4];
        int row = i4 / 75, c4 = i4 - row * 75;
        short* dp = cst + row * CST + c4 * 4;
        dp[0] = f2bf(v.x); dp[1] = f2bf(v.y); dp[2] = f2bf(v.z); dp[3] = f2bf(v.w);
      }
    }
    for (int k = tid; k < 320; k += 256) {  // zero tail k=300..319, all 32 rows
      int row = k / 10, c = (k - row * 10) * 2;
      cst[row * CST + 300 + c] = 0;
      cst[row * CST + 301 + c] = 0;
    }
    __syncthreads();
    const short* arow = cst + (g * 16 + t) * CST;
    f32x4 acc[4] = {};
#pragma unroll
    for (int kk = 0; kk < 10; ++kk) {
      const int k = kk * 32 + quad * 8;
      short8 a = *(const short8*)(arow + k);
#pragma unroll
      for (int n = 0; n < 4; ++n) {
        short8 w8 = *(const short8*)(wpad + ((hf * 4 + n) * 16 + t) * EP + k);
        acc[n] = MFMA16(a, w8, acc[n]);
      }
    }
#pragma unroll
    for (int n = 0; n < 4; ++n) {
      const int h = (hf * 4 + n) * 16 + t;
      const float bv = bias[h];
#pragma unroll
      for (int r = 0; r < 4; ++r) {
        float v = fmaxf(acc[n][r] + bv, 0.0f);
        clt[(i * 32 + g * 16 + quad * 4 + r) * 136 + h] = f2bf(v);  // D -> A layout
      }
    }
    __syncthreads();  // clt written; cst free for next half / qch
  }

  // A-fragments for this wave's 16 rows
  short8 af[4];
#pragma unroll
  for (int kk = 0; kk < 4; ++kk)
    af[kk] = *(const short8*)&clt[(w * 16 + t) * 136 + kk * 32 + quad * 8];

  // ---- phase B: S in 4 q-chunks of 128, LDS-staged with register prefetch ----
  f32x4 s[32];
  const short8* qsrc = (const short8*)(ql + (size_t)b * SQ * HH);
  short8 ld[8];
#pragma unroll
  for (int j = 0; j < 8; ++j) ld[j] = qsrc[tid + j * 256];  // chunk 0
#pragma unroll
  for (int c = 0; c < 4; ++c) {
    if (c) __syncthreads();  // prev chunk MFMA reads done (c=0 covered by phase A barrier + af drain)
#pragma unroll
    for (int j = 0; j < 8; ++j) {
      int i = tid + j * 256;
      int row = i >> 4, c16 = i & 15;
      *(short8*)&qch[row * 136 + c16 * 8] = ld[j];
    }
    __syncthreads();
    if (c < 3) {
#pragma unroll
      for (int j = 0; j < 8; ++j) ld[j] = qsrc[(c + 1) * 2048 + tid + j * 256];  // prefetch
    }
#pragma unroll
    for (int n2 = 0; n2 < 8; ++n2) {
      f32x4 sv = {0.f, 0.f, 0.f, 0.f};
      const short* qrow = qch + (n2 * 16 + t) * 136;
#pragma unroll
      for (int kk = 0; kk < 4; ++kk) {
        short8 b8 = *(const short8*)(qrow + kk * 32 + quad * 8);
        sv = MFMA16(af[kk], b8, sv);
      }
      s[c * 8 + n2] = sv;
    }
  }

  // ---- mask bias + wave-local softmax ----
#pragma unroll
  for (int n = 0; n < 32; ++n) {
    const float mb = maskb[(n >> 3) * 128 + (n & 7) * 16 + t];
    s[n][0] += mb; s[n][1] += mb; s[n][2] += mb; s[n][3] += mb;
  }
  f32x4 rmax = s[0];
#pragma unroll
  for (int n = 1; n < 32; ++n)
#pragma unroll
    for (int r = 0; r < 4; ++r) rmax[r] = fmaxf(rmax[r], s[n][r]);
#pragma unroll
  for (int off = 8; off; off >>= 1)
#pragma unroll
    for (int r = 0; r < 4; ++r) rmax[r] = fmaxf(rmax[r], __shfl_xor(rmax[r], off));
  f32x4 rsum = {0.f, 0.f, 0.f, 0.f};
#pragma unroll
  for (int n = 0; n < 32; ++n)
#pragma unroll
    for (int r = 0; r < 4; ++r) {
      float p = exp2f((s[n][r] - rmax[r]) * LOG2E);
      s[n][r] = p;
      rsum[r] += p;
    }
#pragma unroll
  for (int off = 8; off; off >>= 1)
#pragma unroll
    for (int r = 0; r < 4; ++r) rsum[r] += __shfl_xor(rsum[r], off);

  // ---- phase C: O += P_chunk @ V_chunk (V staged from qlT, prefetched; P wave-private)
  const short8* vsrc = (const short8*)(qlT + (size_t)b * HH * SQ);
#pragma unroll
  for (int j = 0; j < 8; ++j) {
    int i = tid + j * 256;
    ld[j] = vsrc[(i >> 4) * 64 + (i & 15)];  // chunk 0
  }
  f32x4 o[8] = {};
#pragma unroll
  for (int c = 0; c < 4; ++c) {
    __syncthreads();  // prev chunk (or phase B) qch readers done
#pragma unroll
    for (int j = 0; j < 8; ++j) {
      int i = tid + j * 256;
      int row = i >> 4, c16 = i & 15;
      *(short8*)&qch[row * 136 + c16 * 8] = ld[j];
    }
#pragma unroll
    for (int n2 = 0; n2 < 8; ++n2)  // P: D-layout regs -> A-layout LDS (wave-private)
#pragma unroll
      for (int r = 0; r < 4; ++r)
        pbw[(quad * 4 + r) * 136 + n2 * 16 + t] = f2bf(s[c * 8 + n2][r]);
    __syncthreads();
    if (c < 3) {
#pragma unroll
      for (int j = 0; j < 8; ++j) {
        int i = tid + j * 256;
        ld[j] = vsrc[(i >> 4) * 64 + (c + 1) * 16 + (i & 15)];  // prefetch
      }
    }
#pragma unroll
    for (int kk = 0; kk < 4; ++kk) {
      short8 pa = *(const short8*)&pbw[t * 136 + kk * 32 + quad * 8];
#pragma unroll
      for (int n = 0; n < 8; ++n) {
        short8 v8 = *(const short8*)&qch[(n * 16 + t) * 136 + kk * 32 + quad * 8];
        o[n] = MFMA16(pa, v8, o[n]);
      }
    }
  }

  // ---- epilogue ----
  f32x4 rinv;
#pragma unroll
  for (int r = 0; r < 4; ++r) rinv[r] = 1.0f / rsum[r];
  float* obase = out + ((size_t)b * SCTX + m0 + w * 16) * HH;
#pragma unroll
  for (int n = 0; n < 8; ++n)
#pragma unroll
    for (int r = 0; r < 4; ++r)
      obase[(quad * 4 + r) * HH + n * 16 + t] = o[n][r] * rinv[r];
}

extern "C" void kernel_launch(void* const* d_in, const int* in_sizes, int n_in,
                              void* d_out, int out_size, void* d_ws, size_t ws_size,
                              hipStream_t stream) {
  const float* ctx  = (const float*)d_in[0];
  const float* qst  = (const float*)d_in[1];
  const int*   mask = (const int*)d_in[2];
  const float* W    = (const float*)d_in[3];
  const float* bias = (const float*)d_in[4];
  float* out = (float*)d_out;

  // ws: wpad 80 KiB | ql 1 MiB | qlT 1 MiB
  short* wpad = (short*)d_ws;
  short* ql   = (short*)((char*)d_ws + 81920);
  short* qlT  = ql + (size_t)BB * SQ * HH;

  k_wpad<<<dim3(HH), dim3(EP), 0, stream>>>(W, wpad);
  k_qlog<<<dim3(SQ / 32, BB), dim3(256), 0, stream>>>(qst, wpad, bias, ql, qlT);
  k_attn<<<dim3(SCTX / 64, BB), dim3(256), 0, stream>>>(ctx, wpad, bias, mask, ql, qlT, out);
}